// Round 2
// baseline (790.120 us; speedup 1.0000x reference)
//
#include <hip/hip_runtime.h>
#include <cstdint>
#include <cstddef>

// Problem constants (compile-time per reference)
#define BB 64
#define SS 1024
#define HH 1024
#define NSS 8

// scale i: size = 1024>>i, stride = size/2, n_i = 1024/stride - 1 = 2^(i+1)-1
// P rows padded per scale to multiple of 128: region = 64*(n_i+1) = 128*2^i rows
__device__ __constant__ int PBrow_c[8]    = {0,128,384,896,1920,3968,8064,16256};   // padded row base per scale
// magic inverse for div by ni=2^(i+1)-1: b = (local*minv)>>32 (exact for local<2^14)
__device__ __constant__ uint32_t minv_c[8] = {0u, 0x55555556u, 0x24924925u, 0x11111112u,
                                              0x08421085u, 0x04104105u, 0x02040811u, 0x01010102u};
// total padded rows = 32640 (=255*128), total real rows = 32128

#define INV32 0.03125f   // 1/sqrt(H) = 1/sqrt(H*T)

typedef __attribute__((ext_vector_type(8))) short short8;   // 8 bf16 (4 VGPRs)
typedef __attribute__((ext_vector_type(4))) float f32x4;

__device__ __forceinline__ uint16_t f2bf(float f) {
  union { float f; uint32_t u; } v; v.f = f;
  uint32_t r = v.u + 0x7fffu + ((v.u >> 16) & 1u);   // RNE; inputs are finite/bounded
  return (uint16_t)(r >> 16);
}
__device__ __forceinline__ float bf_lo(uint32_t w) { return __uint_as_float(w << 16); }
__device__ __forceinline__ float bf_hi(uint32_t w) { return __uint_as_float(w & 0xffff0000u); }

// tanh via v_exp_f32 + v_rcp_f32: ~6 VALU ops vs libm tanhf's ~25-30.
// err ~1e-7 abs, two orders below bf16 quantization of the stored result.
__device__ __forceinline__ float fast_tanh(float x) {
  const float ax = __builtin_fabsf(x);
  const float t  = __builtin_amdgcn_exp2f(ax * -2.885390081777927f);  // e^{-2|x|}
  const float r  = (1.0f - t) * __builtin_amdgcn_rcpf(1.0f + t);
  return __builtin_copysignf(r, x);
}

// async global->LDS, 16 bytes per lane. LDS dest is wave-uniform base + lane*16.
__device__ __forceinline__ void gld_lds16(const void* g, void* l) {
  __builtin_amdgcn_global_load_lds((const __attribute__((address_space(1))) uint32_t*)g,
                                   (__attribute__((address_space(3))) uint32_t*)l, 16, 0, 0);
}

// Packed tile layout for MFMA operands (the exact LDS staging image):
// elem (row, k) of a 128-row tile group lives at
//   [tile=row>>7][kb2=k>>6][kq=(k>>3)&7][rl=row&127][j=k&7]
__device__ __forceinline__ size_t pk_idx(int row, int k) {
  return (((size_t)(row >> 7) * 16 + (k >> 6)) * 8 + ((k >> 3) & 7)) * 1024
         + (size_t)(row & 127) * 8 + (k & 7);
}

// ---------------------------------------------------------------------------
// Skinny GEMM: out[64][1024] (+)= A[64][1024] @ W (+ bias + addb), split-K=8
// ---------------------------------------------------------------------------
template<bool TRANSB>
__global__ __launch_bounds__(256) void gemm64(
    const float* __restrict__ A, size_t a_stride,
    const float* __restrict__ W,
    const float* __restrict__ bias,
    const float* __restrict__ addb,
    float* __restrict__ out)
{
  __shared__ float As[64][68];   // [k][m], pad 68 keeps float4 16B-aligned
  __shared__ float Bs[64][68];   // [k][n]
  const int t  = threadIdx.x;
  const int nt = blockIdx.x;     // 16 n-tiles of 64
  const int ks = blockIdx.y;     // 8 k-splits of 128
  const int m0 = (t >> 4) << 2;
  const int n0 = (t & 15) << 2;
  float acc[4][4] = {};
  for (int kt = 0; kt < 2; ++kt) {
    const int k0 = ks * 128 + kt * 64;
    { // A tile 64x64 -> As[k][m]
      const int m  = t >> 2;
      const int kb = (t & 3) << 4;
      #pragma unroll
      for (int j = 0; j < 4; ++j) {
        const int k = kb + j * 4;
        const float4 v = *(const float4*)(A + (size_t)m * a_stride + k0 + k);
        As[k+0][m] = v.x; As[k+1][m] = v.y; As[k+2][m] = v.z; As[k+3][m] = v.w;
      }
    }
    if (!TRANSB) {
      const int k  = t >> 2;
      const int nb = (t & 3) << 4;
      #pragma unroll
      for (int j = 0; j < 4; ++j) {
        const int n = nb + j * 4;
        *(float4*)&Bs[k][n] = *(const float4*)(W + (size_t)(k0 + k) * HH + nt * 64 + n);
      }
    } else {
      const int n  = t >> 2;
      const int kb = (t & 3) << 4;
      #pragma unroll
      for (int j = 0; j < 4; ++j) {
        const int k = kb + j * 4;
        const float4 v = *(const float4*)(W + (size_t)(nt * 64 + n) * HH + k0 + k);
        Bs[k+0][n] = v.x; Bs[k+1][n] = v.y; Bs[k+2][n] = v.z; Bs[k+3][n] = v.w;
      }
    }
    __syncthreads();
    #pragma unroll 16
    for (int k = 0; k < 64; ++k) {
      const float4 av = *(const float4*)&As[k][m0];
      const float4 bv = *(const float4*)&Bs[k][n0];
      const float a[4] = {av.x, av.y, av.z, av.w};
      const float b[4] = {bv.x, bv.y, bv.z, bv.w};
      #pragma unroll
      for (int i2 = 0; i2 < 4; ++i2)
        #pragma unroll
        for (int j2 = 0; j2 < 4; ++j2)
          acc[i2][j2] += a[i2] * b[j2];
    }
    __syncthreads();
  }
  #pragma unroll
  for (int i2 = 0; i2 < 4; ++i2) {
    const int m = m0 + i2;
    #pragma unroll
    for (int j2 = 0; j2 < 4; ++j2) {
      const int n = nt * 64 + n0 + j2;
      float v = acc[i2][j2];
      if (ks == 0) {
        if (bias) v += bias[n];
        if (addb) v += addb[(size_t)m * HH + n];
      }
      atomicAdd(out + (size_t)m * HH + n, v);
    }
  }
}

// ---------------------------------------------------------------------------
// scale_importance = softmax(x_last @ Ws + bs) per batch  (tiny)
// ---------------------------------------------------------------------------
__global__ __launch_bounds__(256) void si_kernel(const float* __restrict__ x,
    const float* __restrict__ Ws, const float* __restrict__ bs,
    float* __restrict__ si)
{
  const int b = blockIdx.x, t = threadIdx.x;
  const int n = t & 7, kc = t >> 3;            // 32 k-chunks of 32
  const float* xl = x + ((size_t)b * SS + (SS - 1)) * HH;
  float p = 0.f;
  for (int kk = 0; kk < 32; ++kk) {
    const int k = kc * 32 + kk;
    p += xl[k] * Ws[k * NSS + n];
  }
  __shared__ float red[32][9];
  __shared__ float lg[8];
  red[kc][n] = p;
  __syncthreads();
  if (t < 8) {
    float s2 = bs[t];
    for (int c = 0; c < 32; ++c) s2 += red[c][t];
    lg[t] = s2;
  }
  __syncthreads();
  if (t == 0) {
    float mx = lg[0];
    #pragma unroll
    for (int j = 1; j < 8; ++j) mx = fmaxf(mx, lg[j]);
    float e[8]; float sm = 0.f;
    #pragma unroll
    for (int j = 0; j < 8; ++j) { e[j] = expf(lg[j] - mx); sm += e[j]; }
    const float inv = 1.0f / sm;
    #pragma unroll
    for (int j = 0; j < 8; ++j) si[b * NSS + j] = e[j] * inv;
  }
}

// ---------------------------------------------------------------------------
// score logits: attn[b][s] = (x[b,s,:] . qk[b,:]) * 1/32
// ---------------------------------------------------------------------------
__global__ __launch_bounds__(256) void score_kernel(const float* __restrict__ x,
    const float* __restrict__ qk, float* __restrict__ attn)
{
  const int b = blockIdx.y, sc = blockIdx.x;   // 128 chunks of 8 s
  const int t = threadIdx.x;
  const int lane = t & 63, w = t >> 6;
  __shared__ float qks[HH];
  __shared__ float red[8][4];
  *(float4*)&qks[t * 4] = *(const float4*)&qk[b * HH + t * 4];
  __syncthreads();
  for (int ss = 0; ss < 8; ++ss) {
    const int s = sc * 8 + ss;
    const float4 xv = *(const float4*)&x[((size_t)b * SS + s) * HH + t * 4];
    const float4 qv = *(const float4*)&qks[t * 4];
    float p = xv.x * qv.x + xv.y * qv.y + xv.z * qv.z + xv.w * qv.w;
    #pragma unroll
    for (int off = 32; off > 0; off >>= 1) p += __shfl_down(p, off);
    if (lane == 0) red[ss][w] = p;
  }
  __syncthreads();
  if (t < 8) {
    const float v = (red[t][0] + red[t][1] + red[t][2] + red[t][3]) * INV32;
    attn[(size_t)b * SS + sc * 8 + t] = v;
  }
}

// softmax over S=1024, in place
__global__ __launch_bounds__(256) void softmax_s(float* __restrict__ attn)
{
  const int b = blockIdx.x, t = threadIdx.x;
  float* row = attn + (size_t)b * SS;
  float4 v = *(float4*)&row[t * 4];
  float mx = fmaxf(fmaxf(v.x, v.y), fmaxf(v.z, v.w));
  #pragma unroll
  for (int off = 32; off > 0; off >>= 1) mx = fmaxf(mx, __shfl_xor(mx, off));
  __shared__ float rm[4];
  __shared__ float rs[4];
  if ((t & 63) == 0) rm[t >> 6] = mx;
  __syncthreads();
  mx = fmaxf(fmaxf(rm[0], rm[1]), fmaxf(rm[2], rm[3]));
  const float e0 = expf(v.x - mx), e1 = expf(v.y - mx), e2 = expf(v.z - mx), e3 = expf(v.w - mx);
  float sm = e0 + e1 + e2 + e3;
  #pragma unroll
  for (int off = 32; off > 0; off >>= 1) sm += __shfl_xor(sm, off);
  if ((t & 63) == 0) rs[t >> 6] = sm;
  __syncthreads();
  sm = rs[0] + rs[1] + rs[2] + rs[3];
  const float inv = 1.0f / sm;
  v.x = e0 * inv; v.y = e1 * inv; v.z = e2 * inv; v.w = e3 * inv;
  *(float4*)&row[t * 4] = v;
}

// ---------------------------------------------------------------------------
// One streaming pass over x per (b,h): all 8 pooling scales -> P rows (bf16,
// packed tile layout), plus xa[b,h]. s unrolled by 32: only 4 waves/CU, so
// deep unroll = more outstanding loads (32x256B/wave in flight vs 16).
// ---------------------------------------------------------------------------
__global__ __launch_bounds__(256) void pool_kernel(const float* __restrict__ x,
    const float* __restrict__ attn, uint16_t* __restrict__ P,
    float* __restrict__ xa)
{
  const int b = blockIdx.y;
  const int h = blockIdx.x * 256 + threadIdx.x;
  __shared__ float at[SS];
  #pragma unroll
  for (int j = 0; j < 4; ++j) at[threadIdx.x + j * 256] = attn[(size_t)b * SS + threadIdx.x + j * 256];
  __syncthreads();
  const float* xp = x + (size_t)b * SS * HH + h;
  float lacc[8] = {0,0,0,0,0,0,0,0};
  float lprev[8] = {0,0,0,0,0,0,0,0};
  float xacc = 0.f, chunk = 0.f;
  for (int s32 = 0; s32 < 32; ++s32) {
    float v[32];
    #pragma unroll
    for (int j = 0; j < 32; ++j) v[j] = xp[(size_t)(s32 * 32 + j) * HH];
    #pragma unroll
    for (int j = 0; j < 32; ++j) {
      const int s = s32 * 32 + j;
      xacc += at[s] * v[j];
      chunk += v[j];
      if ((j & 3) == 3) {
        const int cidx = s >> 2;
        const float c = chunk; chunk = 0.f;
        #pragma unroll
        for (int L = 0; L < 8; ++L) {
          lacc[L] += c;
          if (((cidx + 1) & ((1 << L) - 1)) == 0) {
            const int mh = ((cidx + 1) >> L) - 1;   // completed half-window idx
            if (mh >= 1) {
              const int i  = 7 - L;
              const int ni = (256 >> L) - 1;
              const int row = PBrow_c[i] + b * ni + (mh - 1);
              const float inv_size = 1.0f / (float)(8 << L);
              P[pk_idx(row, h)] = f2bf((lprev[L] + lacc[L]) * inv_size);
            }
            lprev[L] = lacc[L]; lacc[L] = 0.f;
          }
        }
      }
    }
  }
  xa[(size_t)b * HH + h] = xacc;
}

// ---------------------------------------------------------------------------
// Wp fp32 [s][k][n] -> Wpk bf16 packed
// ---------------------------------------------------------------------------
__global__ __launch_bounds__(256) void wcvt(const float* __restrict__ Wp,
                                            uint16_t* __restrict__ Wpk)
{
  __shared__ float tile[32][33];
  const int s = blockIdx.z;
  const int n0 = blockIdx.x * 32, k0 = blockIdx.y * 32;
  const float* src = Wp + (size_t)s * HH * HH;
  uint16_t* dst = Wpk + (size_t)s * HH * HH;
  const int t = threadIdx.x;
  #pragma unroll
  for (int i = 0; i < 4; ++i) {
    const int kl = i * 8 + (t >> 5), nl = t & 31;
    tile[kl][nl] = src[(size_t)(k0 + kl) * HH + n0 + nl];
  }
  __syncthreads();
  #pragma unroll
  for (int i = 0; i < 4; ++i) {
    const int nl = i * 8 + (t >> 5), kl = t & 31;
    dst[pk_idx(n0 + nl, k0 + kl)] = f2bf(tile[kl][nl]);
  }
}

// ---------------------------------------------------------------------------
// feat = tanh(P @ Wp[scale]^T + bp[scale])  via MFMA bf16.
// 2-phase double-buffered pipeline (T3-minimum): issue kb2+1's
// global_load_lds BEFORE computing kb2, so __syncthreads()'s vmcnt(0) drain
// lands after ~400cy of MFMA has hidden the load latency. (Old code staged
// then immediately drained: zero overlap -> MfmaUtil 17.6%.)
// Fused fa-logit epilogue: l[row] += (tanh_row . q[b(row)]) * INV32 via
// per-scale magic-div for b(row), 4-step shfl_xor reduce, 1 atomic/row/block.
// Kills the falogit kernel + its 66MB feat re-read; uses f32 tanh values
// (closer to reference than the old bf16 round-trip).
// ---------------------------------------------------------------------------
__global__ __launch_bounds__(256) void feat_gemm(const uint16_t* __restrict__ P,
    const uint16_t* __restrict__ Wpk, const float* __restrict__ bp,
    const float* __restrict__ q, uint16_t* __restrict__ feat,
    float* __restrict__ l)
{
  __shared__ __align__(16) uint16_t As[2][8 * 128 * 8];   // 2 x 16 KB
  __shared__ __align__(16) uint16_t Bs[2][8 * 128 * 8];   // 2 x 16 KB
  const int t = threadIdx.x;
  const int w = t >> 6, lane = t & 63;
  const int quad = lane >> 4, l16 = lane & 15;
  // XCD-aware remap of (ty, ct): nwg=2040=8*255; each XCD gets 255
  // consecutive linear ids = all 8 ct of ~32 consecutive ty.
  const int wg  = blockIdx.y * 8 + blockIdx.x;   // dispatch-linear id
  const int lin = (wg & 7) * 255 + (wg >> 3);    // xcd*chunk + pos
  const int ty  = lin >> 3;
  const int ct  = lin & 7;                       // B col-tile index
  const int scale = 31 - __clz(ty + 1);          // tiles per scale = 2^i
  const int tloc  = ty - ((1 << scale) - 1);
  const int row0  = PBrow_c[scale] + tloc * 128;
  const int rt    = row0 >> 7;                   // A row-tile index
  const float* bps = bp + scale * HH;
  const int ncol0 = ct * 128;
  const int wm = (w & 1) * 64, wn = (w >> 1) * 64;

  f32x4 acc[4][4];
  #pragma unroll
  for (int mt = 0; mt < 4; ++mt)
    #pragma unroll
    for (int nt = 0; nt < 4; ++nt)
      acc[mt][nt] = (f32x4){0.f, 0.f, 0.f, 0.f};

  auto stage = [&](int buf, int kb2) {
    const uint16_t* Ag = P   + ((size_t)(rt * 16 + kb2)) * 8192;
    const uint16_t* Bg = Wpk + ((size_t)((scale * 8 + ct) * 16 + kb2)) * 8192;
    // 16 x 1KB contiguous bursts per operand, 4 per wave
    #pragma unroll
    for (int i = w; i < 16; i += 4) {
      gld_lds16(Ag + i * 512 + lane * 8, &As[buf][i * 512]);
      gld_lds16(Bg + i * 512 + lane * 8, &Bs[buf][i * 512]);
    }
  };

  stage(0, 0);
  __syncthreads();              // vmcnt(0) drain: buf0 ready
  int cur = 0;
  for (int kb2 = 0; kb2 < 16; ++kb2) {
    if (kb2 < 15) stage(cur ^ 1, kb2 + 1);      // prefetch: in flight during MFMA
    const short8* Asv = (const short8*)As[cur];
    const short8* Bsv = (const short8*)Bs[cur];
    #pragma unroll
    for (int ks2 = 0; ks2 < 2; ++ks2) {
      short8 af[4], bf[4];
      #pragma unroll
      for (int mt = 0; mt < 4; ++mt) af[mt] = Asv[(ks2 * 4 + quad) * 128 + wm + mt * 16 + l16];
      #pragma unroll
      for (int nt = 0; nt < 4; ++nt) bf[nt] = Bsv[(ks2 * 4 + quad) * 128 + wn + nt * 16 + l16];
      #pragma unroll
      for (int mt = 0; mt < 4; ++mt)
        #pragma unroll
        for (int nt = 0; nt < 4; ++nt)
          acc[mt][nt] = __builtin_amdgcn_mfma_f32_16x16x32_bf16(af[mt], bf[nt], acc[mt][nt], 0, 0, 0);
    }
    __syncthreads();            // drains prefetch (landed under compute) + all waves done with cur
    cur ^= 1;
  }

  // epilogue: bias + fast tanh + bf16 store + fused fa-logit partial dot
  const uint32_t minv = minv_c[scale];
  float pr[4][4];
  #pragma unroll
  for (int mt = 0; mt < 4; ++mt)
    #pragma unroll
    for (int r = 0; r < 4; ++r) pr[mt][r] = 0.f;
  #pragma unroll
  for (int nt = 0; nt < 4; ++nt) {
    const int col = ncol0 + wn + nt * 16 + l16;
    const float bpv = bps[col];
    #pragma unroll
    for (int mt = 0; mt < 4; ++mt) {
      #pragma unroll
      for (int r = 0; r < 4; ++r) {
        const int row = row0 + wm + mt * 16 + quad * 4 + r;
        const int local = row - PBrow_c[scale];
        const int b = (scale == 0) ? local
                    : (int)(((uint64_t)(uint32_t)local * minv) >> 32);
        const float tv = fast_tanh(acc[mt][nt][r] + bpv);
        feat[(size_t)row * HH + col] = f2bf(tv);
        if (b < 64) pr[mt][r] += tv * q[(size_t)b * HH + col];  // real rows only
      }
    }
  }
  #pragma unroll
  for (int mt = 0; mt < 4; ++mt) {
    #pragma unroll
    for (int r = 0; r < 4; ++r) {
      float p = pr[mt][r];
      p += __shfl_xor(p, 1); p += __shfl_xor(p, 2);
      p += __shfl_xor(p, 4); p += __shfl_xor(p, 8);   // reduce 16 lanes of same row
      const int row = row0 + wm + mt * 16 + quad * 4 + r;
      const int local = row - PBrow_c[scale];
      const int b = (scale == 0) ? local
                  : (int)(((uint64_t)(uint32_t)local * minv) >> 32);
      if (l16 == 0 && b < 64) atomicAdd(&l[row], p * INV32);
    }
  }
}

// ---------------------------------------------------------------------------
// per (scale,b): fa = softmax(l), ctx = fa@feat, combined += si*ctx (atomic)
// ---------------------------------------------------------------------------
__global__ __launch_bounds__(256) void ctx_kernel(const uint16_t* __restrict__ feat,
    const float* __restrict__ l, const float* __restrict__ si,
    float* __restrict__ comb)
{
  const int i = blockIdx.x, b = blockIdx.y, t = threadIdx.x;
  const int ni = (2 << i) - 1;
  const int base = PBrow_c[i] + b * ni;
  __shared__ float fa[256];
  __shared__ float rbuf[4];
  const float lg = (t < ni) ? l[base + t] : -1e30f;
  float mx = lg;
  #pragma unroll
  for (int off = 32; off > 0; off >>= 1) mx = fmaxf(mx, __shfl_xor(mx, off));
  if ((t & 63) == 0) rbuf[t >> 6] = mx;
  __syncthreads();
  mx = fmaxf(fmaxf(rbuf[0], rbuf[1]), fmaxf(rbuf[2], rbuf[3]));
  const float e = (t < ni) ? expf(lg - mx) : 0.f;
  float sm = e;
  #pragma unroll
  for (int off = 32; off > 0; off >>= 1) sm += __shfl_xor(sm, off);
  __syncthreads();
  if ((t & 63) == 0) rbuf[t >> 6] = sm;
  __syncthreads();
  sm = rbuf[0] + rbuf[1] + rbuf[2] + rbuf[3];
  fa[t] = e / sm;
  __syncthreads();
  float c0 = 0.f, c1 = 0.f, c2 = 0.f, c3 = 0.f;
  const int hb = t * 4;
  for (int n = 0; n < ni; ++n) {
    const float fn = fa[n];
    const uint2 u = *(const uint2*)(feat + (size_t)(base + n) * HH + hb);
    c0 += fn * bf_lo(u.x);
    c1 += fn * bf_hi(u.x);
    c2 += fn * bf_lo(u.y);
    c3 += fn * bf_hi(u.y);
  }
  const float sw = si[b * NSS + i];
  atomicAdd(&comb[(size_t)b * HH + hb + 0], sw * c0);
  atomicAdd(&comb[(size_t)b * HH + hb + 1], sw * c1);
  atomicAdd(&comb[(size_t)b * HH + hb + 2], sw * c2);
  atomicAdd(&comb[(size_t)b * HH + hb + 3], sw * c3);
}

// ---------------------------------------------------------------------------
extern "C" void kernel_launch(void* const* d_in, const int* in_sizes, int n_in,
                              void* d_out, int out_size, void* d_ws, size_t ws_size,
                              hipStream_t stream) {
  (void)in_sizes; (void)n_in; (void)out_size; (void)ws_size;
  const float* x  = (const float*)d_in[0];
  const float* Wq = (const float*)d_in[1];
  const float* bq = (const float*)d_in[2];
  const float* Wk = (const float*)d_in[3];
  // d_in[4] = bk: provably unused (constant shift inside softmax)
  const float* Wv = (const float*)d_in[5];
  const float* bv = (const float*)d_in[6];
  const float* Wp = (const float*)d_in[7];
  const float* bp = (const float*)d_in[8];
  const float* Ws = (const float*)d_in[9];
  const float* bs = (const float*)d_in[10];
  const float* Wo = (const float*)d_in[11];
  const float* bo = (const float*)d_in[12];
  float* out = (float*)d_out;
  char* ws = (char*)d_ws;

  const size_t P_BYTES   = (size_t)32640 * HH * 2;   // 66,846,720
  const size_t WPT_BYTES = (size_t)NSS * HH * HH * 2; // 16,777,216
  uint16_t* P    = (uint16_t*)ws;                     // packed layout
  uint16_t* feat = (uint16_t*)(ws + P_BYTES);         // row-major
  uint16_t* Wpk  = (uint16_t*)(ws + 2 * P_BYTES);     // packed layout
  float* q    = (float*)(ws + 2 * P_BYTES + WPT_BYTES);
  float* qk   = q    + (size_t)BB * HH;
  float* comb = qk   + (size_t)BB * HH;
  float* D    = comb + (size_t)BB * HH;
  float* l    = D    + (size_t)BB * HH;      // 32640 padded-row logits
  float* attn = l    + 32640;
  float* xa   = attn + (size_t)BB * SS;
  float* si   = xa   + (size_t)BB * HH;

  // zero atomic-accumulated buffers (q, qk, comb, D, l contiguous) + d_out
  hipMemsetAsync(q, 0, ((size_t)4 * BB * HH + 32640) * sizeof(float), stream);
  hipMemsetAsync(d_out, 0, (size_t)BB * HH * sizeof(float), stream);

  // Wp -> bf16 packed [scale][col-tile][kb2][kq][col][j] for MFMA B-operand
  wcvt<<<dim3(32, 32, NSS), 256, 0, stream>>>(Wp, Wpk);
  // q = x_last @ Wq + bq
  gemm64<false><<<dim3(16, 8), 256, 0, stream>>>(x + (size_t)(SS - 1) * HH, (size_t)SS * HH, Wq, bq, nullptr, q);
  // scale_importance
  si_kernel<<<BB, 256, 0, stream>>>(x, Ws, bs, si);
  // qk = Wk @ q (per batch)
  gemm64<true><<<dim3(16, 8), 256, 0, stream>>>(q, (size_t)HH, Wk, nullptr, nullptr, qk);
  // attention logits over x, pass 1
  score_kernel<<<dim3(128, BB), 256, 0, stream>>>(x, qk, attn);
  softmax_s<<<BB, 256, 0, stream>>>(attn);
  // pooling hierarchy + attn-weighted x accumulation, pass 2
  pool_kernel<<<dim3(4, BB), 256, 0, stream>>>(x, attn, P, xa);
  // feat = tanh(P @ Wp^T + bp) via bf16 MFMA, 2-phase pipeline, fused fa-logits
  feat_gemm<<<dim3(8, 255), 256, 0, stream>>>(P, Wpk, bp, q, feat, l);
  // fa softmax + ctx + combine
  ctx_kernel<<<dim3(NSS, BB), 256, 0, stream>>>(feat, l, si, comb);
  // D = xa @ Wv + bv + combined   (= base_context + combined)
  gemm64<false><<<dim3(16, 8), 256, 0, stream>>>(xa, (size_t)HH, Wv, bv, comb, D);
  // out = D @ Wo + bo
  gemm64<false><<<dim3(16, 8), 256, 0, stream>>>(D, (size_t)HH, Wo, bo, nullptr, out);
}